// Round 6
// baseline (1611.824 us; speedup 1.0000x reference)
//
#include <hip/hip_runtime.h>

#define BB  512
#define SS  100
#define DD  512
#define DFF 256
#define HIDN 230
#define NPAD 240       // mlpf_w padded N (15 tiles of 16)
#define ROWS 32        // rows per k_main block
#define NTHR 512       // k_main threads (8 waves)

typedef unsigned short u16;
typedef unsigned int   u32;
typedef __attribute__((ext_vector_type(8))) short v8s;  // 8 bf16 MFMA frag
typedef __attribute__((ext_vector_type(4))) float v4f;  // 4 f32 accum

__device__ __forceinline__ float b2f(u16 u){
  union { u32 i; float f; } v; v.i = ((u32)u) << 16; return v.f;
}
__device__ __forceinline__ u16 f2b(float f){
  union { float f; u32 i; } v; v.f = f;
  u32 r = (v.i + 0x7fffu + ((v.i >> 16) & 1u)) >> 16;  // RNE
  return (u16)r;
}
__device__ __forceinline__ float rsum16(float s){
  #pragma unroll
  for (int o = 1; o < 16; o <<= 1) s += __shfl_xor(s, o, 64);
  return s;
}

// ---- swizzled LDS layout: 32 rows x 512 bf16, row stride 512 (no pad).
// phys chunk (16B) = (logical_chunk + row) & 63  -> A-frag b128 reads and
// strided LN accesses both land <=2 lanes/bank (free).
__device__ __forceinline__ int sw_off(int row, int col){
  return (row << 9) + ((((col >> 3) + row) & 63) << 3) + (col & 7);
}
__device__ __forceinline__ const u16* frag_ptr(const u16* buf, int row, int ck){
  return buf + (row << 9) + (((ck + row) & 63) << 3);
}

// one col-tile, two row-tiles (rows m and 16+m), K-dot via mfma 16x16x32
// wf = fragment-linear weights: chunk c holds 64 lanes x 16B, c = t*(K/32)+kk
template<int K>
__device__ __forceinline__ void tile_mm2(const u16* __restrict__ abuf,
    int m, int q, const u16* __restrict__ wf, v4f& d0, v4f& d1){
  #pragma unroll
  for (int kk = 0; kk < K/32; kk++){
    v8s bf  = *(const v8s*)(wf + (size_t)kk*512);
    v8s af0 = *(const v8s*)frag_ptr(abuf, m,      kk*4 + q);
    v8s af1 = *(const v8s*)frag_ptr(abuf, 16 + m, kk*4 + q);
    d0 = __builtin_amdgcn_mfma_f32_16x16x32_bf16(af0, bf, d0, 0, 0, 0);
    d1 = __builtin_amdgcn_mfma_f32_16x16x32_bf16(af1, bf, d1, 0, 0, 0);
  }
}

// custom LN (unbiased std, eps added to std) over 512 cols; 16 thr/row.
__device__ __forceinline__ void ln_custom_pass(int lrow, int lc,
    const u16* src, u16* dst, const float* xadd,
    const u16* __restrict__ g, const u16* __restrict__ bb)
{
  float v[32]; float s = 0.f;
  #pragma unroll
  for (int j = 0; j < 32; j++){
    float x = b2f(src[sw_off(lrow, lc + j*16)]); v[j] = x; s += x;
  }
  s = rsum16(s);
  float mean = s * (1.0f/512.0f);
  float vs = 0.f;
  #pragma unroll
  for (int j = 0; j < 32; j++){ float d = v[j] - mean; vs += d*d; }
  vs = rsum16(vs);
  float inv = 1.0f / (sqrtf(vs * (1.0f/511.0f)) + 1e-6f);
  #pragma unroll
  for (int j = 0; j < 32; j++){
    int col = lc + j*16;
    float r = b2f(g[col]) * (v[j] - mean) * inv + b2f(bb[col]);
    if (xadd) r += xadd[j];
    dst[sw_off(lrow, col)] = f2b(r);
  }
}

// ---------------- k_shuf: f32 W[N][K] -> bf16 fragment-linear ----------------
// dst[i]: c=i/512 chunk, lane=(i%512)/8, j=i%8; q=lane>>4, m=lane&15,
// t=c/(K/32), kk=c%(K/32); src = W[16t+m][kk*32+q*8+j] (0 if row >= Nsrc)
__global__ __launch_bounds__(256) void k_shuf(const float* __restrict__ src,
    u16* __restrict__ dst, int Np, int K, int Nsrc)
{
  int total = Np * K;
  int KK = K >> 5;
  for (int i = blockIdx.x*256 + threadIdx.x; i < total; i += gridDim.x*256){
    int c = i >> 9, r = i & 511;
    int ln = r >> 3, j = r & 7;
    int qq = ln >> 4, mm = ln & 15;
    int t = c / KK, kk = c - t*KK;
    int n = t*16 + mm;
    float v = (n < Nsrc) ? src[(size_t)n*K + kk*32 + qq*8 + j] : 0.f;
    dst[i] = f2b(v);
  }
}

// ---------------- k_vec: convert small f32 vectors -> bf16 ----------------
// off[] are RELATIVE to dst (off[0] == 0).
#define NVEC 14
struct VecArgs {
  const float* src[NVEC];
  u16* dst;
  int off[NVEC];
  int n[NVEC];
};
__global__ __launch_bounds__(256) void k_vec(VecArgs a){
  int total = a.off[NVEC-1] + a.n[NVEC-1];
  for (int i = blockIdx.x*256 + threadIdx.x; i < total; i += gridDim.x*256){
    int s = 0;
    #pragma unroll
    for (int j = 1; j < NVEC; j++) if (i >= a.off[j]) s = j;
    a.dst[i] = f2b(a.src[s][i - a.off[s]]);
  }
}

// ---------------- K1: per-batch attention collapse (all f32) ----------------
// wave-per-output-row GEMV: lanes split K, coalesced float4 weight reads,
// sia/sim/cm/cu preloaded into per-lane registers (no LDS in inner loop).
__global__ __launch_bounds__(256) void k_batch(
    const float* __restrict__ inp, const int* __restrict__ mask,
    const float* __restrict__ wv, const float* __restrict__ bv,
    const float* __restrict__ fcw, const float* __restrict__ fcb,
    float* __restrict__ a_m, float* __restrict__ a_u)
{
  __shared__ float sia[DD], sim[DD], cm[DD], cu[DD];
  __shared__ int ncnt;
  const int b = blockIdx.x, t = threadIdx.x;
  const int lane = t & 63, w = t >> 6;
  if (t == 0){
    int c = 0;
    for (int s = 0; s < SS; s++) c += (mask[b*SS + s] != 0);
    ncnt = c;
  }
  const float* base = inp + (size_t)b * SS * DD;
  float aa0 = 0, aa1 = 0, am0 = 0, am1 = 0;
  for (int s = 0; s < SS; s++){
    float x0 = base[s*DD + t];
    float x1 = base[s*DD + t + 256];
    aa0 += x0; aa1 += x1;
    if (mask[b*SS + s]){ am0 += x0; am1 += x1; }
  }
  sia[t] = aa0; sia[t+256] = aa1; sim[t] = am0; sim[t+256] = am1;
  __syncthreads();
  const int n = ncnt;
  const float e0 = expf(1e-8f - 1.0f);   // softmax over {1 x n, 1e-8 x (S-n)}
  const float denom = (float)n + (float)(SS - n) * e0;
  const float p1 = 1.0f / denom, p0 = e0 / denom;

  float4 A0 = *(const float4*)&sia[lane*4];
  float4 A1 = *(const float4*)&sia[256 + lane*4];
  float4 M0 = *(const float4*)&sim[lane*4];
  float4 M1 = *(const float4*)&sim[256 + lane*4];
  for (int d = w; d < DD; d += 4){
    const float4* wr = (const float4*)(wv + (size_t)d * DD);
    float4 w0 = wr[lane], w1 = wr[64 + lane];
    float sva = w0.x*A0.x + w0.y*A0.y + w0.z*A0.z + w0.w*A0.w
              + w1.x*A1.x + w1.y*A1.y + w1.z*A1.z + w1.w*A1.w;
    float svm = w0.x*M0.x + w0.y*M0.y + w0.z*M0.z + w0.w*M0.w
              + w1.x*M1.x + w1.y*M1.y + w1.z*M1.z + w1.w*M1.w;
    #pragma unroll
    for (int o = 1; o < 64; o <<= 1){
      sva += __shfl_xor(sva, o, 64);
      svm += __shfl_xor(svm, o, 64);
    }
    if (lane == 0){
      float bvd = bv[d];
      float sa = sva + (float)SS * bvd;
      float sm = svm + (float)n  * bvd;
      cm[d] = p1*sm + p0*(sa - sm);
      cu[d] = sa * (1.0f/(float)SS);
    }
  }
  __syncthreads();
  float4 C0 = *(const float4*)&cm[lane*4];
  float4 C1 = *(const float4*)&cm[256 + lane*4];
  float4 U0 = *(const float4*)&cu[lane*4];
  float4 U1 = *(const float4*)&cu[256 + lane*4];
  for (int d = w; d < DD; d += 4){
    const float4* fr = (const float4*)(fcw + (size_t)d * DD);
    float4 f0 = fr[lane], f1 = fr[64 + lane];
    float xm = f0.x*C0.x + f0.y*C0.y + f0.z*C0.z + f0.w*C0.w
             + f1.x*C1.x + f1.y*C1.y + f1.z*C1.z + f1.w*C1.w;
    float xu = f0.x*U0.x + f0.y*U0.y + f0.z*U0.z + f0.w*U0.w
             + f1.x*U1.x + f1.y*U1.y + f1.z*U1.z + f1.w*U1.w;
    #pragma unroll
    for (int o = 1; o < 64; o <<= 1){
      xm += __shfl_xor(xm, o, 64);
      xu += __shfl_xor(xu, o, 64);
    }
    if (lane == 0){
      float fb = fcb[d];
      a_m[(size_t)b*DD + d] = xm + fb;
      a_u[(size_t)b*DD + d] = xu + fb;
    }
  }
}

// ---------------- K2: fused per-row chain, 32 rows/block, 8 waves ----------------
__global__ __launch_bounds__(NTHR, 4) void k_main(
    const float* __restrict__ inp, const int* __restrict__ mask,
    const u16* __restrict__ lnm_g, const u16* __restrict__ lnm_b,
    const u16* __restrict__ w1,   const u16* __restrict__ b1,
    const u16* __restrict__ w2,   const u16* __restrict__ b2v,
    const u16* __restrict__ lpc_w, const u16* __restrict__ lpc_b,
    const u16* __restrict__ lnc_g, const u16* __restrict__ lnc_b,
    const u16* __restrict__ pwf_w, const u16* __restrict__ pwf_b,
    const u16* __restrict__ lpi_w, const u16* __restrict__ lpi_b,
    const u16* __restrict__ lni_g, const u16* __restrict__ lni_b,
    const u16* __restrict__ lnf_g, const u16* __restrict__ lnf_b,
    const u16* __restrict__ mlpf_w, const u16* __restrict__ mlpf_b,
    const float* __restrict__ a_m, const float* __restrict__ a_u,
    float* __restrict__ out)
{
  __shared__ __align__(16) u16 AbS[ROWS*512];  // 32 KB
  __shared__ __align__(16) u16 ObS[ROWS*512];  // 32 KB  (total = 64 KB exactly)

  const int tid  = threadIdx.x;
  const int lane = tid & 63, wid = tid >> 6;   // wid 0..7
  const int m = lane & 15, q = lane >> 4;
  const int r0 = blockIdx.x * ROWS;
  const int lrow = tid >> 4, lc = tid & 15;    // LN: 32 rows x 16 threads

  float x32[32];   // this thread's slice of x (inp), LN layout, lives in VGPRs

  // ---- LN1 (torch LN): mha = LN(a_sel + x) -> AbS ; x -> x32 regs ----
  {
    int Rg = r0 + lrow;
    int bi = Rg / SS;
    const float* xrow = inp + (size_t)Rg * DD;
    const float* asel = (mask[Rg] ? a_m : a_u) + (size_t)bi * DD;
    float v[32]; float s = 0.f;
    #pragma unroll
    for (int j = 0; j < 32; j++){
      int col = lc + j*16;
      float xv = xrow[col]; x32[j] = xv;
      float x = asel[col] + xv;
      v[j] = x; s += x;
    }
    s = rsum16(s);
    float mean = s * (1.0f/512.0f);
    float vs = 0.f;
    #pragma unroll
    for (int j = 0; j < 32; j++){ float d = v[j] - mean; vs += d*d; }
    vs = rsum16(vs);
    float inv = 1.0f / sqrtf(vs * (1.0f/512.0f) + 1e-5f);
    #pragma unroll
    for (int j = 0; j < 32; j++){
      int col = lc + j*16;
      float r = b2f(lnm_g[col]) * (v[j] - mean) * inv + b2f(lnm_b[col]);
      AbS[sw_off(lrow, col)] = f2b(r);
    }
  }
  __syncthreads();

  // ---- G1: h1 = relu(mha @ w1^T + b1) -> ObS ; N=256, K=512 ----
  for (int t = wid; t < 16; t += 8){
    v4f d0 = {0.f,0.f,0.f,0.f}, d1 = {0.f,0.f,0.f,0.f};
    const u16* wf = w1 + (size_t)t*16*512 + lane*8;
    tile_mm2<512>(AbS, m, q, wf, d0, d1);
    int col = t*16 + m;
    float bias = b2f(b1[col]);
    #pragma unroll
    for (int i = 0; i < 4; i++){
      float u0 = d0[i] + bias, u1 = d1[i] + bias;
      ObS[sw_off(q*4+i,    col)] = f2b(u0 > 0.f ? u0 : 0.f);
      ObS[sw_off(16+q*4+i, col)] = f2b(u1 > 0.f ? u1 : 0.f);
    }
  }
  __syncthreads();

  // ---- G2: ffn = h1 @ w2^T + b2 ; write (ffn + mha) -> ObS ; N=512, K=256 ----
  {
    v4f d[4][2];
    #pragma unroll
    for (int ti = 0; ti < 4; ti++){
      v4f z = {0.f,0.f,0.f,0.f};
      d[ti][0] = z; d[ti][1] = z;
      int t = wid + ti*8;
      const u16* wf = w2 + (size_t)t*8*512 + lane*8;
      tile_mm2<256>(ObS, m, q, wf, d[ti][0], d[ti][1]);
    }
    __syncthreads();   // all waves done reading h1 from ObS
    #pragma unroll
    for (int ti = 0; ti < 4; ti++){
      int t = wid + ti*8, col = t*16 + m;
      float bias = b2f(b2v[col]);
      #pragma unroll
      for (int i = 0; i < 4; i++){
        int ra = q*4 + i, rb = 16 + q*4 + i;
        ObS[sw_off(ra, col)] = f2b(d[ti][0][i] + bias + b2f(AbS[sw_off(ra, col)]));
        ObS[sw_off(rb, col)] = f2b(d[ti][1][i] + bias + b2f(AbS[sw_off(rb, col)]));
      }
    }
  }
  __syncthreads();

  // ---- LN2 (custom, lni): y = LNc(ffn+mha) + x -> AbS ----
  ln_custom_pass(lrow, lc, ObS, AbS, x32, lni_g, lni_b);
  __syncthreads();

  // ---- G3: z = y @ lpc^T + 2*lpc_b -> ObS ; N=512, K=512 ----
  for (int t = wid; t < 32; t += 8){
    v4f d0 = {0.f,0.f,0.f,0.f}, d1 = {0.f,0.f,0.f,0.f};
    const u16* wf = lpc_w + (size_t)t*16*512 + lane*8;
    tile_mm2<512>(AbS, m, q, wf, d0, d1);
    int col = t*16 + m;
    float bias = 2.0f * b2f(lpc_b[col]);
    #pragma unroll
    for (int i = 0; i < 4; i++){
      ObS[sw_off(q*4+i,    col)] = f2b(d0[i] + bias);
      ObS[sw_off(16+q*4+i, col)] = f2b(d1[i] + bias);
    }
  }
  __syncthreads();

  // ---- LN3 (custom, lnc): res_inp = LNc(z) -> AbS ----
  ln_custom_pass(lrow, lc, ObS, AbS, nullptr, lnc_g, lnc_b);
  __syncthreads();

  // ---- G4: h2 = relu(res_inp @ pwf^T + pwf_b) -> ObS ; N=256, K=512 ----
  for (int t = wid; t < 16; t += 8){
    v4f d0 = {0.f,0.f,0.f,0.f}, d1 = {0.f,0.f,0.f,0.f};
    const u16* wf = pwf_w + (size_t)t*16*512 + lane*8;
    tile_mm2<512>(AbS, m, q, wf, d0, d1);
    int col = t*16 + m;
    float bias = b2f(pwf_b[col]);
    #pragma unroll
    for (int i = 0; i < 4; i++){
      float u0 = d0[i] + bias, u1 = d1[i] + bias;
      ObS[sw_off(q*4+i,    col)] = f2b(u0 > 0.f ? u0 : 0.f);
      ObS[sw_off(16+q*4+i, col)] = f2b(u1 > 0.f ? u1 : 0.f);
    }
  }
  __syncthreads();

  // ---- G5: rv = h2 @ lpi^T + lpi_b ; write (rv + res_inp) -> AbS ; N=512, K=256 ----
  {
    v4f d[4][2];
    #pragma unroll
    for (int ti = 0; ti < 4; ti++){
      v4f z = {0.f,0.f,0.f,0.f};
      d[ti][0] = z; d[ti][1] = z;
      int t = wid + ti*8;
      const u16* wf = lpi_w + (size_t)t*8*512 + lane*8;
      tile_mm2<256>(ObS, m, q, wf, d[ti][0], d[ti][1]);
    }
    __syncthreads();   // all waves done reading h2 (ObS) and res_inp A-frags (AbS)
    #pragma unroll
    for (int ti = 0; ti < 4; ti++){
      int t = wid + ti*8, col = t*16 + m;
      float bias = b2f(lpi_b[col]);
      #pragma unroll
      for (int i = 0; i < 4; i++){
        int ra = q*4 + i, rb = 16 + q*4 + i;
        AbS[sw_off(ra, col)] = f2b(d[ti][0][i] + bias + b2f(AbS[sw_off(ra, col)]));
        AbS[sw_off(rb, col)] = f2b(d[ti][1][i] + bias + b2f(AbS[sw_off(rb, col)]));
      }
    }
  }
  __syncthreads();

  // ---- LN4 (custom, lnf): res = LNc(rv+res_inp) -> ObS ----
  ln_custom_pass(lrow, lc, AbS, ObS, nullptr, lnf_g, lnf_b);
  __syncthreads();

  // ---- G6: out = res @ mlpf^T + mlpf_b ; N=240 (padded), K=512, f32 stores ----
  for (int t = wid; t < 15; t += 8){
    v4f d0 = {0.f,0.f,0.f,0.f}, d1 = {0.f,0.f,0.f,0.f};
    const u16* wf = mlpf_w + (size_t)t*16*512 + lane*8;
    tile_mm2<512>(ObS, m, q, wf, d0, d1);
    int col = t*16 + m;
    if (col < HIDN){
      float bias = b2f(mlpf_b[col]);
      #pragma unroll
      for (int i = 0; i < 4; i++){
        out[(size_t)(r0 + q*4 + i)*HIDN + col]      = d0[i] + bias;
        out[(size_t)(r0 + 16 + q*4 + i)*HIDN + col] = d1[i] + bias;
      }
    }
  }
}

extern "C" void kernel_launch(void* const* d_in, const int* in_sizes, int n_in,
                              void* d_out, int out_size, void* d_ws, size_t ws_size,
                              hipStream_t stream)
{
  const float* inp    = (const float*)d_in[0];
  const int*   mask   = (const int*)d_in[1];
  // d_in[2] = gate: dead computation in the reference
  const float* wv     = (const float*)d_in[3];
  const float* bv     = (const float*)d_in[4];
  const float* fc_w   = (const float*)d_in[5];
  const float* fc_b   = (const float*)d_in[6];

  // ws: a_m f32[512*512] | a_u f32[512*512] | bf16 fragment-linear weights + vectors
  float* a_m = (float*)d_ws;
  float* a_u = a_m + (size_t)BB * DD;
  u16* bfb = (u16*)((char*)d_ws + 2u * BB * DD * sizeof(float));

  const int OW1   = 0;                     // 256x512
  const int OW2   = OW1  + DFF*DD;         // 512x256
  const int OLPC  = OW2  + DD*DFF;         // 512x512
  const int OPWF  = OLPC + DD*DD;          // 256x512
  const int OLPI  = OPWF + DFF*DD;         // 512x256
  const int OMLPF = OLPI + DD*DFF;         // 240x512 (padded)
  const int OVEC  = OMLPF + NPAD*DD;       // vector region base
  // relative (to OVEC) vector offsets
  int voff = 0;
  const int RLNMG = voff; voff += DD;
  const int RLNMB = voff; voff += DD;
  const int RB1   = voff; voff += DFF;
  const int RB2   = voff; voff += DD;
  const int RLPCB = voff; voff += DD;
  const int RLNCG = voff; voff += DD;
  const int RLNCB = voff; voff += DD;
  const int RPWFB = voff; voff += DFF;
  const int RLPIB = voff; voff += DD;
  const int RLNIG = voff; voff += DD;
  const int RLNIB = voff; voff += DD;
  const int RLNFG = voff; voff += DD;
  const int RLNFB = voff; voff += DD;
  const int RMLPFB = voff; voff += HIDN;

  // fragment-shuffle the 6 matrices
  k_shuf<<<512,  256, 0, stream>>>((const float*)d_in[9],  bfb + OW1,   DFF,  DD,  DFF);
  k_shuf<<<512,  256, 0, stream>>>((const float*)d_in[11], bfb + OW2,   DD,   DFF, DD);
  k_shuf<<<1024, 256, 0, stream>>>((const float*)d_in[13], bfb + OLPC,  DD,   DD,  DD);
  k_shuf<<<512,  256, 0, stream>>>((const float*)d_in[17], bfb + OPWF,  DFF,  DD,  DFF);
  k_shuf<<<512,  256, 0, stream>>>((const float*)d_in[19], bfb + OLPI,  DD,   DFF, DD);
  k_shuf<<<480,  256, 0, stream>>>((const float*)d_in[25], bfb + OMLPF, NPAD, DD,  HIDN);

  VecArgs va;
  const int vsrc[NVEC]  = {7, 8, 10, 12, 14, 15, 16, 18, 20, 21, 22, 23, 24, 26};
  const int voffs[NVEC] = {RLNMG, RLNMB, RB1, RB2, RLPCB, RLNCG, RLNCB, RPWFB,
                           RLPIB, RLNIG, RLNIB, RLNFG, RLNFB, RMLPFB};
  const int vlens[NVEC] = {DD, DD, DFF, DD, DD, DD, DD, DFF, DD, DD, DD, DD, DD, HIDN};
  for (int i = 0; i < NVEC; i++){
    va.src[i] = (const float*)d_in[vsrc[i]];
    va.off[i] = voffs[i];
    va.n[i]   = vlens[i];
  }
  va.dst = bfb + OVEC;                     // RELATIVE offsets, dst at vector base
  k_vec<<<25, 256, 0, stream>>>(va);

  k_batch<<<BB, 256, 0, stream>>>(inp, mask, wv, bv, fc_w, fc_b, a_m, a_u);

  k_main<<<(BB*SS)/ROWS, NTHR, 0, stream>>>(inp, mask,
      bfb + OVEC + RLNMG, bfb + OVEC + RLNMB,
      bfb + OW1,   bfb + OVEC + RB1,
      bfb + OW2,   bfb + OVEC + RB2,
      bfb + OLPC,  bfb + OVEC + RLPCB,
      bfb + OVEC + RLNCG, bfb + OVEC + RLNCB,
      bfb + OPWF,  bfb + OVEC + RPWFB,
      bfb + OLPI,  bfb + OVEC + RLPIB,
      bfb + OVEC + RLNIG, bfb + OVEC + RLNIB,
      bfb + OVEC + RLNFG, bfb + OVEC + RLNFB,
      bfb + OMLPF, bfb + OVEC + RMLPFB,
      a_m, a_u, (float*)d_out);
}